// Round 1
// baseline (875.924 us; speedup 1.0000x reference)
//
#include <hip/hip_runtime.h>

typedef unsigned short ushort_t;
typedef __attribute__((ext_vector_type(8))) short short8;
typedef __attribute__((ext_vector_type(4))) float floatx4;

#define B_ROWS 16384
#define BO 16777216  // B*O

__device__ __forceinline__ ushort_t f2bf(float f){
  unsigned u = __float_as_uint(f);
  u += 0x7fffu + ((u >> 16) & 1u);
  return (ushort_t)(u >> 16);
}

__device__ __forceinline__ void gld_lds16(void* l, const void* g){
  __builtin_amdgcn_global_load_lds(
      (__attribute__((address_space(1))) void*)(g),
      (__attribute__((address_space(3))) void*)(l), 16, 0, 0);
}

// ---------------- x f32 -> bf16 ----------------
__global__ void cvt_x(const float* __restrict__ x, ushort_t* __restrict__ xb){
  const int i = (blockIdx.x * 256 + threadIdx.x) * 4;
  const floatx4 v = *(const floatx4*)(x + i);
  ushort4 o;
  o.x = f2bf(v[0]); o.y = f2bf(v[1]); o.z = f2bf(v[2]); o.w = f2bf(v[3]);
  *(ushort4*)(xb + i) = o;
}

// ---------------- W f32 [12][D][O] -> bf16 transposed [12][O][D] ----------------
__global__ void cvt_wt(const float* __restrict__ W, ushort_t* __restrict__ wt){
  __shared__ float t[64][65];
  const int blk = blockIdx.x;              // 12*16*16
  const int ge = blk >> 8, dt = (blk >> 4) & 15, ot = blk & 15;
  const float* src = W + ((size_t)ge << 20) + (size_t)(dt * 64) * 1024 + ot * 64;
  const int c4 = (threadIdx.x & 15) * 4, r0 = threadIdx.x >> 4;
#pragma unroll
  for (int p = 0; p < 4; ++p){
    const int r = r0 + p * 16;
    const floatx4 v = *(const floatx4*)(src + (size_t)r * 1024 + c4);
    t[r][c4] = v[0]; t[r][c4+1] = v[1]; t[r][c4+2] = v[2]; t[r][c4+3] = v[3];
  }
  __syncthreads();
  ushort_t* dst = wt + ((size_t)ge << 20) + (size_t)(ot * 64) * 1024 + dt * 64;
  const int d4 = (threadIdx.x & 15) * 4, o0 = threadIdx.x >> 4;
#pragma unroll
  for (int p = 0; p < 4; ++p){
    const int o = o0 + p * 16;
    ushort4 ov;
    ov.x = f2bf(t[d4][o]);   ov.y = f2bf(t[d4+1][o]);
    ov.z = f2bf(t[d4+2][o]); ov.w = f2bf(t[d4+3][o]);
    *(ushort4*)(dst + (size_t)o * 1024 + d4) = ov;
  }
}

// ---------------- gates: selT[28][B] ----------------
__global__ void gates_kernel(const float* __restrict__ x,
                             const float* __restrict__ Wg,
                             const float* __restrict__ bg,
                             const float* __restrict__ Wgs,
                             const float* __restrict__ bgs,
                             float* __restrict__ selT)
{
  const int lane = threadIdx.x & 63;
  const int w    = threadIdx.x >> 6;
  const int b    = blockIdx.x * 4 + w;
  const float* xr = x + (size_t)b * 1024;

  float acc[28];
#pragma unroll
  for (int m = 0; m < 28; ++m) acc[m] = 0.f;

#pragma unroll
  for (int j = 0; j < 4; ++j){
    const int d0 = (j * 64 + lane) * 4;
    const floatx4 xv = *(const floatx4*)(xr + d0);
#pragma unroll
    for (int q = 0; q < 4; ++q){
      const float xs = xv[q];
      const int d = d0 + q;
      const float* g0 = Wg + d * 8;
      const float* g1 = Wg + 8192 + d * 8;
      const float* gs = Wgs + d * 12;
#pragma unroll
      for (int m = 0; m < 8; ++m)  acc[m]      += xs * g0[m];
#pragma unroll
      for (int m = 0; m < 8; ++m)  acc[8 + m]  += xs * g1[m];
#pragma unroll
      for (int m = 0; m < 12; ++m) acc[16 + m] += xs * gs[m];
    }
  }
#pragma unroll
  for (int m = 0; m < 28; ++m){
    float v = acc[m];
#pragma unroll
    for (int off = 1; off < 64; off <<= 1) v += __shfl_xor(v, off, 64);
    acc[m] = v;
  }
  if (lane == 0){
    float e0[8], e1[8], es[12];
    float mx0 = -1e30f, mx1 = -1e30f, mxs = -1e30f;
#pragma unroll
    for (int m = 0; m < 8; ++m){  e0[m] = acc[m]      + bg[m];     mx0 = fmaxf(mx0, e0[m]); }
#pragma unroll
    for (int m = 0; m < 8; ++m){  e1[m] = acc[8 + m]  + bg[8 + m]; mx1 = fmaxf(mx1, e1[m]); }
#pragma unroll
    for (int m = 0; m < 12; ++m){ es[m] = acc[16 + m] + bgs[m];    mxs = fmaxf(mxs, es[m]); }
    float s0 = 0.f, s1 = 0.f, ss = 0.f;
#pragma unroll
    for (int m = 0; m < 8; ++m){  e0[m] = __expf(e0[m] - mx0); s0 += e0[m]; }
#pragma unroll
    for (int m = 0; m < 8; ++m){  e1[m] = __expf(e1[m] - mx1); s1 += e1[m]; }
#pragma unroll
    for (int m = 0; m < 12; ++m){ es[m] = __expf(es[m] - mxs); ss += es[m]; }
    const float r0 = 1.f / s0, r1 = 1.f / s1, rs = 1.f / ss;
#pragma unroll
    for (int m = 0; m < 8; ++m)  selT[(size_t)m * B_ROWS + b]        = e0[m] * r0;
#pragma unroll
    for (int m = 0; m < 8; ++m)  selT[(size_t)(8 + m) * B_ROWS + b]  = e1[m] * r1;
#pragma unroll
    for (int m = 0; m < 12; ++m) selT[(size_t)(16 + m) * B_ROWS + b] = es[m] * rs;
  }
}

// ---------------- fused MoE GEMM ----------------
// tile 128x64, 4 waves (2M x 2N), wave tile 64x32, BK=64, mfma 16x16x32 bf16
__global__ __launch_bounds__(256, 2) void moe_kernel(
    const ushort_t* __restrict__ xb,   // [16384][1024] bf16
    const ushort_t* __restrict__ wt,   // [12][1024 o][1024 d] bf16
    const float* __restrict__ bias,    // [12][1024]
    const float* __restrict__ selT,    // [28][16384]
    float* __restrict__ out)           // [3][16384][1024]
{
  __shared__ __align__(16) char smem[24576];   // A 16384B + B 8192B
  const int tid  = threadIdx.x;
  const int lane = tid & 63;
  const int wid  = tid >> 6;
  const int wm   = wid >> 1;
  const int wn   = wid & 1;
  const int brow = (blockIdx.x >> 4) << 7;
  const int bcol = (blockIdx.x & 15) << 6;

  // staging: linear LDS dest, inverse-swizzled global source
  const int rstg = tid >> 3;                                   // 0..31
  const int scol = ((tid & 7) << 4) ^ ((rstg & 7) << 4);
  size_t aoff[4], boff[2];
#pragma unroll
  for (int i = 0; i < 4; ++i) aoff[i] = (size_t)(brow + i * 32 + rstg) * 2048 + scol;
#pragma unroll
  for (int i = 0; i < 2; ++i) boff[i] = (size_t)(bcol + i * 32 + rstg) * 2048 + scol;
  char* aldst = smem + wid * 1024;          // wave-uniform base; HW adds lane*16
  char* bldst = smem + 16384 + wid * 1024;

  // fragment read addressing (swizzled)
  const int kl   = (lane >> 4) << 4;        // 0,16,32,48 bytes
  const int swzr = (lane & 7) << 4;
  int arow[4], brw[2];
#pragma unroll
  for (int m = 0; m < 4; ++m) arow[m] = (wm * 64 + m * 16 + (lane & 15)) * 128;
#pragma unroll
  for (int n = 0; n < 2; ++n) brw[n] = 16384 + (wn * 32 + n * 16 + (lane & 15)) * 128;

  const floatx4 fz = {0.f, 0.f, 0.f, 0.f};
  floatx4 o0a[4][2], o1a[4][2], osa[4][2];
#pragma unroll
  for (int m = 0; m < 4; ++m)
#pragma unroll
    for (int n = 0; n < 2; ++n){ o0a[m][n] = fz; o1a[m][n] = fz; osa[m][n] = fz; }

  const int c0 = bcol + wn * 32 + (lane & 15);
  const int rb = brow + wm * 64 + ((lane >> 4) << 2);

  for (int ex = 0; ex < 12; ++ex){
    floatx4 hacc[4][2];
#pragma unroll
    for (int m = 0; m < 4; ++m)
#pragma unroll
      for (int n = 0; n < 2; ++n) hacc[m][n] = fz;

    const size_t wbase = (size_t)ex << 21;   // 1024*2048 bytes per expert
    for (int kt = 0; kt < 16; ++kt){
      const size_t ko = (size_t)kt << 7;
#pragma unroll
      for (int i = 0; i < 4; ++i)
        gld_lds16(aldst + i * 4096, (const char*)xb + aoff[i] + ko);
#pragma unroll
      for (int i = 0; i < 2; ++i)
        gld_lds16(bldst + i * 4096, (const char*)wt + wbase + boff[i] + ko);
      __syncthreads();
#pragma unroll
      for (int kk = 0; kk < 2; ++kk){
        short8 av[4], bv[2];
        const int kb = (kk << 6) + kl;
#pragma unroll
        for (int m = 0; m < 4; ++m)
          av[m] = *(const short8*)(smem + arow[m] + (kb ^ swzr));
#pragma unroll
        for (int n = 0; n < 2; ++n)
          bv[n] = *(const short8*)(smem + brw[n] + (kb ^ swzr));
#pragma unroll
        for (int m = 0; m < 4; ++m)
#pragma unroll
          for (int n = 0; n < 2; ++n)
            hacc[m][n] = __builtin_amdgcn_mfma_f32_16x16x32_bf16(av[m], bv[n], hacc[m][n], 0, 0, 0);
      }
      __syncthreads();
    }

    // epilogue: fold relu(h + bias) into the 3 outputs with gate weights
    const int g = ex >> 2, e = ex & 3;
    const float bi0 = bias[ex * 1024 + c0];
    const float bi1 = bias[ex * 1024 + c0 + 16];
    int i0, i1, is_;
    if (g == 0)      { i0 = e;     i1 = -1;     is_ = 16 + e; }
    else if (g == 1) { i0 = -1;    i1 = 8 + e;  is_ = 20 + e; }
    else             { i0 = 4 + e; i1 = 12 + e; is_ = 24 + e; }

#pragma unroll
    for (int m = 0; m < 4; ++m){
      const int rg = rb + m * 16;
      const floatx4 wsv = *(const floatx4*)(selT + (size_t)is_ * B_ROWS + rg);
      floatx4 w0 = fz, w1 = fz;
      if (i0 >= 0) w0 = *(const floatx4*)(selT + (size_t)i0 * B_ROWS + rg);
      if (i1 >= 0) w1 = *(const floatx4*)(selT + (size_t)i1 * B_ROWS + rg);
#pragma unroll
      for (int n = 0; n < 2; ++n){
        const float bi = n ? bi1 : bi0;
#pragma unroll
        for (int r = 0; r < 4; ++r){
          float h = hacc[m][n][r] + bi;
          h = fmaxf(h, 0.f);
          osa[m][n][r] += wsv[r] * h;
          o0a[m][n][r] += w0[r] * h;
          o1a[m][n][r] += w1[r] * h;
        }
      }
    }
  }

#pragma unroll
  for (int m = 0; m < 4; ++m){
#pragma unroll
    for (int n = 0; n < 2; ++n){
#pragma unroll
      for (int r = 0; r < 4; ++r){
        const size_t idx = (size_t)(rb + m * 16 + r) * 1024 + (c0 + (n << 4));
        out[idx]          = o0a[m][n][r];
        out[idx + BO]     = o1a[m][n][r];
        out[idx + 2 * BO] = osa[m][n][r];
      }
    }
  }
}

extern "C" void kernel_launch(void* const* d_in, const int* in_sizes, int n_in,
                              void* d_out, int out_size, void* d_ws, size_t ws_size,
                              hipStream_t stream) {
  const float* x   = (const float*)d_in[0];
  const float* W   = (const float*)d_in[1];
  const float* b   = (const float*)d_in[2];
  const float* Wg  = (const float*)d_in[3];
  const float* bg  = (const float*)d_in[4];
  const float* Wgs = (const float*)d_in[5];
  const float* bgs = (const float*)d_in[6];
  float* out = (float*)d_out;

  char* ws = (char*)d_ws;
  ushort_t* xb   = (ushort_t*)ws;                      // 33,554,432 B
  ushort_t* wtp  = (ushort_t*)(ws + 33554432);         // 25,165,824 B
  float*    selT = (float*)(ws + 58720256);            //  1,835,008 B

  cvt_x<<<dim3(16384), dim3(256), 0, stream>>>(x, xb);
  cvt_wt<<<dim3(3072), dim3(256), 0, stream>>>(W, wtp);
  gates_kernel<<<dim3(4096), dim3(256), 0, stream>>>(x, Wg, bg, Wgs, bgs, selT);
  moe_kernel<<<dim3(2048), dim3(256), 0, stream>>>(xb, wtp, b, selT, out);
}

// Round 3
// 606.759 us; speedup vs baseline: 1.4436x; 1.4436x over previous
//
#include <hip/hip_runtime.h>

typedef unsigned short ushort_t;
typedef __attribute__((ext_vector_type(8))) short short8;
typedef __attribute__((ext_vector_type(4))) float floatx4;

#define B_ROWS 16384
#define BO 16777216  // B*O
#define MC 4096      // M chunk for two-pass

__device__ __forceinline__ ushort_t f2bf(float f){
  unsigned u = __float_as_uint(f);
  u += 0x7fffu + ((u >> 16) & 1u);
  return (ushort_t)(u >> 16);
}
__device__ __forceinline__ float bf2f(ushort_t u){
  return __uint_as_float(((unsigned)u) << 16);
}

__device__ __forceinline__ void gld_lds16(void* l, const void* g){
  __builtin_amdgcn_global_load_lds(
      (__attribute__((address_space(1))) void*)(g),
      (__attribute__((address_space(3))) void*)(l), 16, 0, 0);
}

// ---------------- x f32 -> bf16 ----------------
__global__ void cvt_x(const float* __restrict__ x, ushort_t* __restrict__ xb){
  const int i = (blockIdx.x * 256 + threadIdx.x) * 4;
  const floatx4 v = *(const floatx4*)(x + i);
  ushort4 o;
  o.x = f2bf(v[0]); o.y = f2bf(v[1]); o.z = f2bf(v[2]); o.w = f2bf(v[3]);
  *(ushort4*)(xb + i) = o;
}

// ---------------- W f32 [12][D][O] -> bf16 transposed [12][O][D] ----------------
__global__ void cvt_wt(const float* __restrict__ W, ushort_t* __restrict__ wt){
  __shared__ float t[64][65];
  const int blk = blockIdx.x;              // 12*16*16
  const int ge = blk >> 8, dt = (blk >> 4) & 15, ot = blk & 15;
  const float* src = W + ((size_t)ge << 20) + (size_t)(dt * 64) * 1024 + ot * 64;
  const int c4 = (threadIdx.x & 15) * 4, r0 = threadIdx.x >> 4;
#pragma unroll
  for (int p = 0; p < 4; ++p){
    const int r = r0 + p * 16;
    const floatx4 v = *(const floatx4*)(src + (size_t)r * 1024 + c4);
    t[r][c4] = v[0]; t[r][c4+1] = v[1]; t[r][c4+2] = v[2]; t[r][c4+3] = v[3];
  }
  __syncthreads();
  ushort_t* dst = wt + ((size_t)ge << 20) + (size_t)(ot * 64) * 1024 + dt * 64;
  const int d4 = (threadIdx.x & 15) * 4, o0 = threadIdx.x >> 4;
#pragma unroll
  for (int p = 0; p < 4; ++p){
    const int o = o0 + p * 16;
    ushort4 ov;
    ov.x = f2bf(t[d4][o]);   ov.y = f2bf(t[d4+1][o]);
    ov.z = f2bf(t[d4+2][o]); ov.w = f2bf(t[d4+3][o]);
    *(ushort4*)(dst + (size_t)o * 1024 + d4) = ov;
  }
}

// ---------------- gate weights -> bf16 [32][1024] (padded, transposed) ----------------
__global__ void cvt_wg(const float* __restrict__ Wg, const float* __restrict__ bg,
                       const float* __restrict__ Wgs, const float* __restrict__ bgs,
                       ushort_t* __restrict__ wgcat, float* __restrict__ biascat){
  const int m = blockIdx.x; // 0..31
#pragma unroll
  for (int j = 0; j < 4; ++j){
    const int d = j * 256 + threadIdx.x;
    float v;
    if (m < 16)      v = Wg[((size_t)((m >> 3) * 1024 + d)) * 8 + (m & 7)];
    else if (m < 28) v = Wgs[(size_t)d * 12 + (m - 16)];
    else             v = 0.f;
    wgcat[m * 1024 + d] = f2bf(v);
  }
  if (threadIdx.x == 0){
    float bv;
    if (m < 16)      bv = bg[m];
    else if (m < 28) bv = bgs[m - 16];
    else             bv = -1e30f;
    biascat[m] = bv;
  }
}

// ---------------- gates via MFMA: selT[28][B] ----------------
// tile 128 rows x 32 cols, 4 waves (32 rows each), BK=64
// THREE softmax groups: cols 0..7 (task0), 8..15 (task1), 16..27 (shared)
__global__ __launch_bounds__(256) void gates_mfma(
    const ushort_t* __restrict__ xb, const ushort_t* __restrict__ wgcat,
    const float* __restrict__ biascat, float* __restrict__ selT)
{
  __shared__ __align__(16) char gsm[20480];  // A 16KB @0, B 4KB @16384
  const int tid = threadIdx.x;
  const int lane = tid & 63;
  const int w = tid >> 6;
  const int lr = lane & 15;
  const int brow = blockIdx.x * 128;

  const int sc = (((tid & 7) ^ ((tid >> 3) & 7)) << 4);
  const char* aS = (const char*)xb + (size_t)(brow + (tid >> 3)) * 2048 + sc;
  const char* bS = (const char*)wgcat + (size_t)(tid >> 3) * 2048 + sc;

  const int kx0 = (((lane >> 4) << 4)) ^ ((lane & 7) << 4);
  const int kx1 = (64 + ((lane >> 4) << 4)) ^ ((lane & 7) << 4);

  int aOff[2], bOff[2];
#pragma unroll
  for (int m = 0; m < 2; ++m) aOff[m] = (w * 32 + m * 16 + lr) * 128;
#pragma unroll
  for (int n = 0; n < 2; ++n) bOff[n] = 16384 + (n * 16 + lr) * 128;

  const floatx4 fz = {0.f, 0.f, 0.f, 0.f};
  floatx4 hacc[2][2];
#pragma unroll
  for (int m = 0; m < 2; ++m)
#pragma unroll
    for (int n = 0; n < 2; ++n) hacc[m][n] = fz;

  for (int kt = 0; kt < 16; ++kt){
    const size_t ko = (size_t)kt * 128;
#pragma unroll
    for (int j = 0; j < 4; ++j)
      gld_lds16(gsm + j * 4096 + w * 1024, aS + (size_t)j * 65536 + ko);
    gld_lds16(gsm + 16384 + w * 1024, bS + ko);
    __syncthreads();   // compiler inserts full vmcnt(0) drain before barrier
    short8 av[2][2], bv[2][2];
#pragma unroll
    for (int m = 0; m < 2; ++m){
      av[m][0] = *(const short8*)(gsm + aOff[m] + kx0);
      av[m][1] = *(const short8*)(gsm + aOff[m] + kx1);
    }
#pragma unroll
    for (int n = 0; n < 2; ++n){
      bv[n][0] = *(const short8*)(gsm + bOff[n] + kx0);
      bv[n][1] = *(const short8*)(gsm + bOff[n] + kx1);
    }
#pragma unroll
    for (int m = 0; m < 2; ++m)
#pragma unroll
      for (int n = 0; n < 2; ++n){
        hacc[m][n] = __builtin_amdgcn_mfma_f32_16x16x32_bf16(av[m][0], bv[n][0], hacc[m][n], 0, 0, 0);
        hacc[m][n] = __builtin_amdgcn_mfma_f32_16x16x32_bf16(av[m][1], bv[n][1], hacc[m][n], 0, 0, 0);
      }
    __syncthreads();
  }

  const float bc0 = biascat[lr];
  const float bc1 = biascat[16 + lr];
#pragma unroll
  for (int m = 0; m < 2; ++m){
#pragma unroll
    for (int r = 0; r < 4; ++r){
      float l0 = hacc[m][0][r] + bc0;   // task logit, col lr (0..15)
      float l1 = hacc[m][1][r] + bc1;   // shared logit, col 16+lr (valid lr<12)
      // task softmax over 8-lane subgroup (bits 0..2 of lane)
      float mx0 = l0;
#pragma unroll
      for (int s = 1; s < 8; s <<= 1) mx0 = fmaxf(mx0, __shfl_xor(mx0, s, 64));
      float e0 = __expf(l0 - mx0);
      float s0 = e0;
#pragma unroll
      for (int s = 1; s < 8; s <<= 1) s0 += __shfl_xor(s0, s, 64);
      // shared softmax over 16-lane group (bits 0..3); pad lanes have l1=-1e30 -> exp 0
      float mx1 = l1;
#pragma unroll
      for (int s = 1; s < 16; s <<= 1) mx1 = fmaxf(mx1, __shfl_xor(mx1, s, 64));
      float e1 = __expf(l1 - mx1);
      float s1 = e1;
#pragma unroll
      for (int s = 1; s < 16; s <<= 1) s1 += __shfl_xor(s1, s, 64);
      const int row = brow + w * 32 + m * 16 + ((lane >> 4) << 2) + r;
      selT[(size_t)lr * B_ROWS + row] = e0 / s0;
      if (lr < 12) selT[(size_t)(16 + lr) * B_ROWS + row] = e1 / s1;
    }
  }
}

// ---------------- pass1: 256x256 4-phase GEMM, one expert-tile per block ----------------
// h_chunk [12][MC][1024] bf16 = relu(x @ W^T + b)
// vmcnt ledger (per wave, 8 gld/iter): at iter-i ph3-end, outstanding =
//   {B0(i+1),A(i+1)}[6] + B1(i+1)@ph0[2] + B0(i+2)@ph2[2] + A(i+2)@ph3[4] = 14
//   vmcnt(6) confirms exactly tile i+1's 8 loads; following barrier publishes them.
//   i==14: only +B1(15)[2] outstanding (8) -> vmcnt(0) to confirm tile 15. i==15: none.
__global__ __launch_bounds__(512, 2) void pass1_gemm(
    const ushort_t* __restrict__ xb,   // [16384][1024]
    const ushort_t* __restrict__ wt,   // [12][1024][1024]
    const float* __restrict__ bias,    // [12][1024]
    ushort_t* __restrict__ h,          // [12][MC][1024]
    int chunk_row0)
{
  __shared__ __align__(16) char smem[131072]; // 2 bufs x (A 32KB + B 32KB)
  const int tid  = threadIdx.x;
  const int lane = tid & 63;
  const int wv   = tid >> 6;       // 0..7
  const int wm   = wv >> 2;        // 0..1
  const int wn   = wv & 3;         // 0..3
  const int lr   = lane & 15;

  // XCD-aware bijective swizzle (768 blocks, 96 per XCD)
  const int bid = blockIdx.x;
  const int L = (bid & 7) * 96 + (bid >> 3);
  const int mt = L / 48;
  const int rr = L % 48;
  const int ex = rr >> 2;
  const int nt = rr & 3;
  const int brow_l = mt * 256;
  const int browg  = chunk_row0 + brow_l;
  const int bcol   = nt * 256;

  // ---- staging addressing ----
  const int sc = (((tid & 7) ^ ((tid >> 3) & 7)) << 4);
  const char* aSrc[2];
  const char* bSrc[2];
#pragma unroll
  for (int hh = 0; hh < 2; ++hh){
    aSrc[hh] = (const char*)xb + (size_t)(browg + hh * 128 + (tid >> 3)) * 2048 + sc;
    bSrc[hh] = (const char*)wt + ((size_t)ex << 21)
             + (size_t)(bcol + hh * 128 + (tid >> 3)) * 2048 + sc;
  }

  auto stageA = [&](int hh, int kt, int bo){
    char* d = smem + bo + hh * 16384 + wv * 1024;
    const char* s = aSrc[hh] + (size_t)kt * 128;
    gld_lds16(d, s);
    gld_lds16(d + 8192, s + 131072);
  };
  auto stageB = [&](int hh, int kt, int bo){
    char* d = smem + bo + 32768 + hh * 16384 + wv * 1024;
    const char* s = bSrc[hh] + (size_t)kt * 128;
    gld_lds16(d, s);
    gld_lds16(d + 8192, s + 131072);
  };

  // ---- fragment read addressing ----
  const int kx0 = (((lane >> 4) << 4)) ^ ((lane & 7) << 4);
  const int kx1 = (64 + ((lane >> 4) << 4)) ^ ((lane & 7) << 4);
  int aOff[8], bOff[4];
#pragma unroll
  for (int m = 0; m < 8; ++m) aOff[m] = wm * 16384 + (m * 16 + lr) * 128;
#pragma unroll
  for (int n = 0; n < 4; ++n)
    bOff[n] = 32768 + (wn >> 1) * 16384 + ((wn & 1) * 64 + n * 16 + lr) * 128;

  const floatx4 fz = {0.f, 0.f, 0.f, 0.f};
  floatx4 hacc[8][4];
#pragma unroll
  for (int m = 0; m < 8; ++m)
#pragma unroll
    for (int n = 0; n < 4; ++n) hacc[m][n] = fz;

  // ---- prologue: tile0 full (8) + tile1 {B0, A} (6) ----
  stageA(0, 0, 0); stageA(1, 0, 0); stageB(0, 0, 0); stageB(1, 0, 0);
  stageB(0, 1, 65536); stageA(0, 1, 65536); stageA(1, 1, 65536);
  asm volatile("s_waitcnt vmcnt(6)" ::: "memory");   // tile0's 8 loads landed
  __builtin_amdgcn_s_barrier();                       // publish to all waves

#define LDF(X) (*(const short8*)(smem + (X)))
#define MFMA_(A, Bv, C) __builtin_amdgcn_mfma_f32_16x16x32_bf16(A, Bv, C, 0, 0, 0)
#define LGKM0_SB() { asm volatile("s_waitcnt lgkmcnt(0)" ::: "memory"); __builtin_amdgcn_sched_barrier(0); }

  for (int i = 0; i < 16; ++i){
    const int cur = (i & 1) << 16;
    const int nxt = cur ^ 65536;

    // ---------- phase 0: read a0,b0(cur); stage B1(i+1)->nxt ----------
    short8 a0[4][2], b0[2][2];
#pragma unroll
    for (int m = 0; m < 4; ++m){
      a0[m][0] = LDF(cur + aOff[m] + kx0);
      a0[m][1] = LDF(cur + aOff[m] + kx1);
    }
#pragma unroll
    for (int n = 0; n < 2; ++n){
      b0[n][0] = LDF(cur + bOff[n] + kx0);
      b0[n][1] = LDF(cur + bOff[n] + kx1);
    }
    if (i + 1 < 16) stageB(1, i + 1, nxt);
    __builtin_amdgcn_s_barrier();
    LGKM0_SB();
    __builtin_amdgcn_s_setprio(1);
#pragma unroll
    for (int m = 0; m < 4; ++m)
#pragma unroll
      for (int n = 0; n < 2; ++n){
        hacc[m][n] = MFMA_(a0[m][0], b0[n][0], hacc[m][n]);
        hacc[m][n] = MFMA_(a0[m][1], b0[n][1], hacc[m][n]);
      }
    __builtin_amdgcn_s_setprio(0);
    __builtin_amdgcn_s_barrier();

    // ---------- phase 1: read b1(cur) ----------
    short8 b1[2][2];
#pragma unroll
    for (int n = 0; n < 2; ++n){
      b1[n][0] = LDF(cur + bOff[2 + n] + kx0);
      b1[n][1] = LDF(cur + bOff[2 + n] + kx1);
    }
    __builtin_amdgcn_s_barrier();
    LGKM0_SB();
    __builtin_amdgcn_s_setprio(1);
#pragma unroll
    for (int m = 0; m < 4; ++m)
#pragma unroll
      for (int n = 0; n < 2; ++n){
        hacc[m][2 + n] = MFMA_(a0[m][0], b1[n][0], hacc[m][2 + n]);
        hacc[m][2 + n] = MFMA_(a0[m][1], b1[n][1], hacc[m][2 + n]);
      }
    __builtin_amdgcn_s_setprio(0);
    __builtin_amdgcn_s_barrier();

    // ---------- phase 2: read a1(cur); stage B0(i+2)->cur B (dead after ph1) ----------
    short8 a1[4][2];
#pragma unroll
    for (int m = 0; m < 4; ++m){
      a1[m][0] = LDF(cur + aOff[4 + m] + kx0);
      a1[m][1] = LDF(cur + aOff[4 + m] + kx1);
    }
    if (i + 2 < 16) stageB(0, i + 2, cur);
    __builtin_amdgcn_s_barrier();
    LGKM0_SB();
    __builtin_amdgcn_s_setprio(1);
#pragma unroll
    for (int m = 0; m < 4; ++m)
#pragma unroll
      for (int n = 0; n < 2; ++n){
        hacc[4 + m][n] = MFMA_(a1[m][0], b0[n][0], hacc[4 + m][n]);
        hacc[4 + m][n] = MFMA_(a1[m][1], b0[n][1], hacc[4 + m][n]);
      }
    __builtin_amdgcn_s_setprio(0);
    __builtin_amdgcn_s_barrier();

    // ---------- phase 3: stage A(i+2)->cur A (dead after ph2); vmcnt at END ----------
    if (i + 2 < 16) { stageA(0, i + 2, cur); stageA(1, i + 2, cur); }
    __builtin_amdgcn_s_barrier();
    __builtin_amdgcn_s_setprio(1);
#pragma unroll
    for (int m = 0; m < 4; ++m)
#pragma unroll
      for (int n = 0; n < 2; ++n){
        hacc[4 + m][2 + n] = MFMA_(a1[m][0], b1[n][0], hacc[4 + m][2 + n]);
        hacc[4 + m][2 + n] = MFMA_(a1[m][1], b1[n][1], hacc[4 + m][2 + n]);
      }
    __builtin_amdgcn_s_setprio(0);
    // confirm tile i+1's loads BEFORE the barrier that precedes its reads
    if (i < 14)       { asm volatile("s_waitcnt vmcnt(6)" ::: "memory"); }
    else if (i == 14) { asm volatile("s_waitcnt vmcnt(0)" ::: "memory"); }
    __builtin_amdgcn_s_barrier();
  }

  // ---- epilogue: relu(h + bias) -> bf16 store ----
  const int colb = bcol + wn * 64 + lr;
  float bi[4];
#pragma unroll
  for (int n = 0; n < 4; ++n) bi[n] = bias[ex * 1024 + colb + n * 16];
  ushort_t* hbase = h + ((size_t)ex * MC) * 1024;
#pragma unroll
  for (int m = 0; m < 8; ++m){
#pragma unroll
    for (int r = 0; r < 4; ++r){
      const int row = brow_l + wm * 128 + m * 16 + ((lane >> 4) << 2) + r;
      ushort_t* hp = hbase + (size_t)row * 1024 + colb;
#pragma unroll
      for (int n = 0; n < 4; ++n){
        float v = hacc[m][n][r] + bi[n];
        hp[n * 16] = f2bf(fmaxf(v, 0.f));
      }
    }
  }
#undef LDF
#undef MFMA_
#undef LGKM0_SB
}

// ---------------- pass2: gate-weighted combine ----------------
__global__ __launch_bounds__(256) void combine_kernel(
    const ushort_t* __restrict__ h,    // [12][MC][1024]
    const float* __restrict__ selT,    // [28][16384]
    float* __restrict__ out,           // [3][16384][1024]
    int row0)
{
  const int tid = threadIdx.x;
  const int lb  = blockIdx.x * 2 + (tid >> 7);
  const int b   = row0 + lb;
  const int c   = (tid & 127) * 8;
  const ushort_t* hp = h + (size_t)lb * 1024 + c;

  float a0[8], a1[8], as_[8];
#pragma unroll
  for (int k = 0; k < 8; ++k){ a0[k] = 0.f; a1[k] = 0.f; as_[k] = 0.f; }

#pragma unroll
  for (int e = 0; e < 4; ++e){  // g0
    const float w0 = selT[(size_t)e * B_ROWS + b];
    const float ws = selT[(size_t)(16 + e) * B_ROWS + b];
    const short8 hv = *(const short8*)(hp + (size_t)e * (MC * 1024));
#pragma unroll
    for (int k = 0; k < 8; ++k){
      const float f = bf2f((ushort_t)hv[k]);
      a0[k] += w0 * f; as_[k] += ws * f;
    }
  }
#pragma unroll
  for (int e = 0; e < 4; ++e){  // g1
    const float w1 = selT[(size_t)(8 + e) * B_ROWS + b];
    const float ws = selT[(size_t)(20 + e) * B_ROWS + b];
    const short8 hv = *(const short8*)(hp + (size_t)(4 + e) * (MC * 1024));
#pragma unroll
    for (int k = 0; k < 8; ++k){
      const float f = bf2f((ushort_t)hv[k]);
      a1[k] += w1 * f; as_[k] += ws * f;
    }
  }
#pragma unroll
  for (int e = 0; e < 4; ++e){  // g2 (shared experts)
    const float w0 = selT[(size_t)(4 + e) * B_ROWS + b];
    const float w1 = selT[(size_t)(12 + e) * B_ROWS + b];
    const float ws = selT[(size_t)(24 + e) * B_ROWS + b];
    const short8 hv = *(const short8*)(hp + (size_t)(8 + e) * (MC * 1024));
#pragma unroll
    for (int k = 0; k < 8; ++k){
      const float f = bf2f((ushort_t)hv[k]);
      a0[k] += w0 * f; a1[k] += w1 * f; as_[k] += ws * f;
    }
  }

  float* o0 = out + (size_t)b * 1024 + c;
  *(floatx4*)(o0)     = *(const floatx4*)(a0);
  *(floatx4*)(o0 + 4) = *(const floatx4*)(a0 + 4);
  float* o1 = o0 + BO;
  *(floatx4*)(o1)     = *(const floatx4*)(a1);
  *(floatx4*)(o1 + 4) = *(const floatx4*)(a1 + 4);
  float* o2 = o1 + BO;
  *(floatx4*)(o2)     = *(const floatx4*)(as_);
  *(floatx4*)(o2 + 4) = *(const floatx4*)(as_ + 4);
}

// ================= fallback (round-1, proven) path =================
__global__ void gates_kernel(const float* __restrict__ x,
                             const float* __restrict__ Wg,
                             const float* __restrict__ bg,
                             const float* __restrict__ Wgs,
                             const float* __restrict__ bgs,
                             float* __restrict__ selT)
{
  const int lane = threadIdx.x & 63;
  const int w    = threadIdx.x >> 6;
  const int b    = blockIdx.x * 4 + w;
  const float* xr = x + (size_t)b * 1024;
  float acc[28];
#pragma unroll
  for (int m = 0; m < 28; ++m) acc[m] = 0.f;
#pragma unroll
  for (int j = 0; j < 4; ++j){
    const int d0 = (j * 64 + lane) * 4;
    const floatx4 xv = *(const floatx4*)(xr + d0);
#pragma unroll
    for (int q = 0; q < 4; ++q){
      const float xs = xv[q];
      const int d = d0 + q;
      const float* g0 = Wg + d * 8;
      const float* g1 = Wg + 8192 + d * 8;
      const float* gs = Wgs + d * 12;
#pragma unroll
      for (int m = 0; m < 8; ++m)  acc[m]      += xs * g0[m];
#pragma unroll
      for (int m = 0; m < 8; ++m)  acc[8 + m]  += xs * g1[m];
#pragma unroll
      for (int m = 0; m < 12; ++m) acc[16 + m] += xs * gs[m];
    }
  }
#pragma unroll
  for (int m = 0; m < 28; ++m){
    float v = acc[m];
#pragma unroll
    for (int off = 1; off < 64; off <<= 1) v += __shfl_xor(v, off, 64);
    acc[m] = v;
  }
  if (lane == 0){
    float e0[8], e1[8], es[12];
    float mx0 = -1e30f, mx1 = -1e30f, mxs = -1e30f;
#pragma unroll
    for (int m = 0; m < 8; ++m){  e0[m] = acc[m]      + bg[m];     mx0 = fmaxf(mx0, e0[m]); }
#pragma unroll
    for (int m = 0; m < 8; ++m){  e1[m] = acc[8 + m]  + bg[8 + m]; mx1 = fmaxf(mx1, e1[m]); }
#pragma unroll
    for (int m = 0; m < 12; ++m){ es[m] = acc[16 + m] + bgs[m];    mxs = fmaxf(mxs, es[m]); }
    float s0 = 0.f, s1 = 0.f, ss = 0.f;
#pragma unroll
    for (int m = 0; m < 8; ++m){  e0[m] = __expf(e0[m] - mx0); s0 += e0[m]; }
#pragma unroll
    for (int m = 0; m < 8; ++m){  e1[m] = __expf(e1[m] - mx1); s1 += e1[m]; }
#pragma unroll
    for (int m = 0; m < 12; ++m){ es[m] = __expf(es[m] - mxs); ss += es[m]; }
    const float r0 = 1.f / s0, r1 = 1.f / s1, rs = 1.f / ss;
#pragma unroll
    for (int m = 0; m < 8; ++m)  selT[(size_t)m * B_ROWS + b]        = e0[m] * r0;
#pragma unroll
    for (int m = 0; m < 8; ++m)  selT[(size_t)(8 + m) * B_ROWS + b]  = e1[m] * r1;
#pragma unroll
    for (int m = 0; m < 12; ++m) selT[(size_t)(16 + m) * B_ROWS + b] = es[m] * rs;
  }
}

__global__ __launch_bounds__(256, 2) void moe_kernel(
    const ushort_t* __restrict__ xb,
    const ushort_t* __restrict__ wt,
    const float* __restrict__ bias,
    const float* __restrict__ selT,
    float* __restrict__ out)
{
  __shared__ __align__(16) char smem[24576];
  const int tid  = threadIdx.x;
  const int lane = tid & 63;
  const int wid  = tid >> 6;
  const int wm   = wid >> 1;
  const int wn   = wid & 1;
  const int brow = (blockIdx.x >> 4) << 7;
  const int bcol = (blockIdx.x & 15) << 6;
  const int rstg = tid >> 3;
  const int scol = ((tid & 7) << 4) ^ ((rstg & 7) << 4);
  size_t aoff[4], boff[2];
#pragma unroll
  for (int i = 0; i < 4; ++i) aoff[i] = (size_t)(brow + i * 32 + rstg) * 2048 + scol;
#pragma unroll
  for (int i = 0; i < 2; ++i) boff[i] = (size_t)(bcol + i * 32 + rstg) * 2048 + scol;
  char* aldst = smem + wid * 1024;
  char* bldst = smem + 16384 + wid * 1024;
  const int kl   = (lane >> 4) << 4;
  const int swzr = (lane & 7) << 4;
  int arow[4], brw[2];
#pragma unroll
  for (int m = 0; m < 4; ++m) arow[m] = (wm * 64 + m * 16 + (lane & 15)) * 128;
#pragma unroll
  for (int n = 0; n < 2; ++n) brw[n] = 16384 + (wn * 32 + n * 16 + (lane & 15)) * 128;
  const floatx4 fz = {0.f, 0.f, 0.f, 0.f};
  floatx4 o0a[4][2], o1a[4][2], osa[4][2];
#pragma unroll
  for (int m = 0; m < 4; ++m)
#pragma unroll
    for (int n = 0; n < 2; ++n){ o0a[m][n] = fz; o1a[m][n] = fz; osa[m][n] = fz; }
  const int c0 = bcol + wn * 32 + (lane & 15);
  const int rb = brow + wm * 64 + ((lane >> 4) << 2);
  for (int ex = 0; ex < 12; ++ex){
    floatx4 hacc[4][2];
#pragma unroll
    for (int m = 0; m < 4; ++m)
#pragma unroll
      for (int n = 0; n < 2; ++n) hacc[m][n] = fz;
    const size_t wbase = (size_t)ex << 21;
    for (int kt = 0; kt < 16; ++kt){
      const size_t ko = (size_t)kt << 7;
#pragma unroll
      for (int i = 0; i < 4; ++i)
        gld_lds16(aldst + i * 4096, (const char*)xb + aoff[i] + ko);
#pragma unroll
      for (int i = 0; i < 2; ++i)
        gld_lds16(bldst + i * 4096, (const char*)wt + wbase + boff[i] + ko);
      __syncthreads();
#pragma unroll
      for (int kk = 0; kk < 2; ++kk){
        short8 av[4], bv[2];
        const int kb = (kk << 6) + kl;
#pragma unroll
        for (int m = 0; m < 4; ++m)
          av[m] = *(const short8*)(smem + arow[m] + (kb ^ swzr));
#pragma unroll
        for (int n = 0; n < 2; ++n)
          bv[n] = *(const short8*)(smem + brw[n] + (kb ^ swzr));
#pragma unroll
        for (int m = 0; m < 4; ++m)
#pragma unroll
          for (int n = 0; n < 2; ++n)
            hacc[m][n] = __builtin_amdgcn_mfma_f32_16x16x32_bf16(av[m], bv[n], hacc[m][n], 0, 0, 0);
      }
      __syncthreads();
    }
    const int g = ex >> 2, e = ex & 3;
    const float bi0 = bias[ex * 1024 + c0];
    const float bi1 = bias[ex * 1024 + c0 + 16];
    int i0, i1, is_;
    if (g == 0)      { i0 = e;     i1 = -1;     is_ = 16 + e; }
    else if (g == 1) { i0 = -1;    i1 = 8 + e;  is_ = 20 + e; }
    else             { i0 = 4 + e; i1 = 12 + e; is_ = 24 + e; }
#pragma unroll
    for (int m = 0; m < 4; ++m){
      const int rg = rb + m * 16;
      const floatx4 wsv = *(const floatx4*)(selT + (size_t)is_ * B_ROWS + rg);
      floatx4 w0 = fz, w1 = fz;
      if (i0 >= 0) w0 = *(const floatx4*)(selT + (size_t)i0 * B_ROWS + rg);
      if (i1 >= 0) w1 = *(const floatx4*)(selT + (size_t)i1 * B_ROWS + rg);
#pragma unroll
      for (int n = 0; n < 2; ++n){
        const float bi = n ? bi1 : bi0;
#pragma unroll
        for (int r = 0; r < 4; ++r){
          float hv = hacc[m][n][r] + bi;
          hv = fmaxf(hv, 0.f);
          osa[m][n][r] += wsv[r] * hv;
          o0a[m][n][r] += w0[r] * hv;
          o1a[m][n][r] += w1[r] * hv;
        }
      }
    }
  }
#pragma unroll
  for (int m = 0; m < 4; ++m){
#pragma unroll
    for (int n = 0; n < 2; ++n){
#pragma unroll
      for (int r = 0; r < 4; ++r){
        const size_t idx = (size_t)(rb + m * 16 + r) * 1024 + (c0 + (n << 4));
        out[idx]          = o0a[m][n][r];
        out[idx + BO]     = o1a[m][n][r];
        out[idx + 2 * BO] = osa[m][n][r];
      }
    }
  }
}

extern "C" void kernel_launch(void* const* d_in, const int* in_sizes, int n_in,
                              void* d_out, int out_size, void* d_ws, size_t ws_size,
                              hipStream_t stream) {
  const float* x   = (const float*)d_in[0];
  const float* W   = (const float*)d_in[1];
  const float* b   = (const float*)d_in[2];
  const float* Wg  = (const float*)d_in[3];
  const float* bg  = (const float*)d_in[4];
  const float* Wgs = (const float*)d_in[5];
  const float* bgs = (const float*)d_in[6];
  float* out = (float*)d_out;

  char* ws = (char*)d_ws;
  ushort_t* xb   = (ushort_t*)ws;                      // 33,554,432 B
  ushort_t* wtp  = (ushort_t*)(ws + 33554432);         // 25,165,824 B
  float*    selT = (float*)(ws + 58720256);            //  1,835,008 B
  ushort_t* wgc  = (ushort_t*)(ws + 60555264);         //     65,536 B
  float*    bcat = (float*)(ws + 60620800);            //        128 B
  ushort_t* hbuf = (ushort_t*)(ws + 67108864);         // 100,663,296 B

  const bool two_pass = ws_size >= (size_t)(67108864 + 12 * MC * 1024 * 2);

  cvt_x<<<dim3(16384), dim3(256), 0, stream>>>(x, xb);
  cvt_wt<<<dim3(3072), dim3(256), 0, stream>>>(W, wtp);

  if (two_pass){
    cvt_wg<<<dim3(32), dim3(256), 0, stream>>>(Wg, bg, Wgs, bgs, wgc, bcat);
    gates_mfma<<<dim3(128), dim3(256), 0, stream>>>(xb, wgc, bcat, selT);
    for (int c = 0; c < 16384 / MC; ++c){
      pass1_gemm<<<dim3((MC / 256) * 48), dim3(512), 0, stream>>>(xb, wtp, b, hbuf, c * MC);
      combine_kernel<<<dim3(MC / 2), dim3(256), 0, stream>>>(hbuf, selT, out, c * MC);
    }
  } else {
    gates_kernel<<<dim3(4096), dim3(256), 0, stream>>>(x, Wg, bg, Wgs, bgs, selT);
    moe_kernel<<<dim3(2048), dim3(256), 0, stream>>>(xb, wtp, b, selT, out);
  }
}